// Round 4
// baseline (650.843 us; speedup 1.0000x reference)
//
#include <hip/hip_runtime.h>
#include <hip/hip_bf16.h>

#define T_DIM 1024
#define B_DIM 16
#define H_DIM 1024
#define L_DIM 3
#define M_DIM (T_DIM * B_DIM)
#define N_DIM (3 * H_DIM)
#define K_DIM H_DIM
#define NC 64
#define CS 16

typedef __bf16 bf16x8 __attribute__((ext_vector_type(8)));
typedef _Float16 half8 __attribute__((ext_vector_type(8)));
typedef float f32x4 __attribute__((ext_vector_type(4)));

__device__ __forceinline__ __bf16 f2bf(float f) {
    return (__bf16)__float2bfloat16(f);
}

__device__ __forceinline__ void async_cp16(const void* g, void* lds) {
    __builtin_amdgcn_global_load_lds(
        (__attribute__((address_space(1))) void*)g,
        (__attribute__((address_space(3))) void*)lds, 16, 0, 0);
}

__global__ void transpose_w(const float* __restrict__ W, __bf16* __restrict__ Wt) {
    __shared__ __bf16 tile[32][33];
    const int l = blockIdx.z;
    const int k0 = blockIdx.x * 32, n0 = blockIdx.y * 32;
    const int tx = threadIdx.x & 31, ty = threadIdx.x >> 5;
    const float* Wl = W + (size_t)l * K_DIM * N_DIM;
    __bf16* Wtl = Wt + (size_t)l * N_DIM * K_DIM;
#pragma unroll
    for (int q = 0; q < 4; q++) {
        int k = ty + q * 8;
        tile[k][tx] = f2bf(Wl[(size_t)(k0 + k) * N_DIM + n0 + tx]);
    }
    __syncthreads();
#pragma unroll
    for (int q = 0; q < 4; q++) {
        int n = ty + q * 8;
        Wtl[(size_t)(n0 + n) * K_DIM + k0 + tx] = tile[tx][n];
    }
}

__global__ void embed_kernel(const int* __restrict__ x,
                             const float4* __restrict__ emb,
                             __bf16* __restrict__ h) {
    int i = blockIdx.x * 256 + threadIdx.x;
    int row = i >> 8;
    int j = i & 255;
    int idx = x[row];
    float4 v = emb[(size_t)idx * 256 + j];
    __bf16* dst = h + (size_t)row * H_DIM + j * 4;
    dst[0] = f2bf(v.x); dst[1] = f2bf(v.y); dst[2] = f2bf(v.z); dst[3] = f2bf(v.w);
}

// GEMM + bias + activation -> fp16 planar gates. XOR-swizzled LDS (slot = c ^ ((r>>1)&3)).
__global__ __launch_bounds__(256, 2) void gemm_gates(
    const __bf16* __restrict__ A,
    const __bf16* __restrict__ Wt,
    const float* __restrict__ bias,
    _Float16* __restrict__ Gz, _Float16* __restrict__ Gf, _Float16* __restrict__ Go) {
    __shared__ __align__(16) __bf16 As[128 * 32];
    __shared__ __align__(16) __bf16 Bs[128 * 32];

    const int tid = threadIdx.x;
    const int wid = tid >> 6, lane = tid & 63;
    const int bm = blockIdx.x, bn = blockIdx.y;
    const int waveM = wid >> 1, waveN = wid & 1;
    const int lm = lane & 15, kg = lane >> 4;

    const int r0 = tid >> 2;
    const int cc = (((tid & 3) ^ ((r0 >> 1) & 3))) * 8;  // swizzled global chunk (elems)
    const int r1 = r0 + 64;                              // (r1>>1)&3 == (r0>>1)&3
    const __bf16* Abase = A + (size_t)(bm * 128) * K_DIM;
    const __bf16* Bbase = Wt + (size_t)(bn * 128) * K_DIM;
    __bf16* ldsA0 = As + (size_t)wid * 512;
    __bf16* ldsA1 = As + (size_t)wid * 512 + 2048;
    __bf16* ldsB0 = Bs + (size_t)wid * 512;
    __bf16* ldsB1 = Bs + (size_t)wid * 512 + 2048;

    const int csw = (kg ^ ((lm >> 1) & 3)) * 8;          // swizzled read chunk (elems)

    f32x4 acc[4][4] = {};

    for (int k0 = 0; k0 < K_DIM; k0 += 32) {
        async_cp16(Abase + (size_t)r0 * K_DIM + k0 + cc, ldsA0);
        async_cp16(Abase + (size_t)r1 * K_DIM + k0 + cc, ldsA1);
        async_cp16(Bbase + (size_t)r0 * K_DIM + k0 + cc, ldsB0);
        async_cp16(Bbase + (size_t)r1 * K_DIM + k0 + cc, ldsB1);
        __syncthreads();

        bf16x8 af[4], bf[4];
#pragma unroll
        for (int i = 0; i < 4; i++)
            af[i] = *(const bf16x8*)(As + (waveM * 64 + i * 16 + lm) * 32 + csw);
#pragma unroll
        for (int j = 0; j < 4; j++)
            bf[j] = *(const bf16x8*)(Bs + (waveN * 64 + j * 16 + lm) * 32 + csw);
#pragma unroll
        for (int i = 0; i < 4; i++)
#pragma unroll
            for (int j = 0; j < 4; j++)
                acc[i][j] = __builtin_amdgcn_mfma_f32_16x16x32_bf16(af[i], bf[j], acc[i][j], 0, 0, 0);
        __syncthreads();
    }

    // epilogue; plane is block-uniform (bn covers 128 cols inside one 1024-col plane).
    // fast-math: v_rcp_f32 (~1ulp) instead of IEEE divide sequence (~10 instrs).
    const int plane = bn >> 3;
    _Float16* __restrict__ P = (plane == 0) ? Gz : (plane == 1) ? Gf : Go;
#pragma unroll
    for (int i = 0; i < 4; i++) {
#pragma unroll
        for (int j = 0; j < 4; j++) {
            int ncol = bn * 128 + waveN * 64 + j * 16 + lm;
            int col = ncol & 1023;
            float bv = bias[ncol];
#pragma unroll
            for (int r = 0; r < 4; r++) {
                int mrow = bm * 128 + waveM * 64 + i * 16 + kg * 4 + r;
                float g = acc[i][j][r] + bv;
                float val;
                if (plane == 0) {
                    // tanh(g) = sign(g) * (1 - 2e/(1+e)), e = exp(-2|g|) <= 1
                    float e = __expf(-2.0f * fabsf(g));
                    float rc = __builtin_amdgcn_rcpf(1.0f + e);
                    val = copysignf(fmaf(-2.0f * e, rc, 1.0f), g);
                } else {
                    // sigmoid(g) = 1/(1+exp(-g)); saturates safely (rcp(inf)=0)
                    float e = __expf(-g);
                    val = __builtin_amdgcn_rcpf(1.0f + e);
                }
                P[(size_t)mrow * H_DIM + col] = (_Float16)val;
            }
        }
    }
}

// scan pass 1: per-chunk affine aggregates, x8 vectorized (16B loads)
__global__ void scan_pass1(const _Float16* __restrict__ Gz, const _Float16* __restrict__ Gf,
                           float* __restrict__ cA, float* __restrict__ cM) {
    int tid = blockIdx.x * 256 + threadIdx.x;   // NC * 2048 = 131072
    int ci = tid >> 11;
    int cg = tid & 2047;                        // channel-group of 8
    size_t base = (size_t)(ci * CS) * 16384 + (size_t)cg * 8;
    float Aacc[8] = {0.f, 0.f, 0.f, 0.f, 0.f, 0.f, 0.f, 0.f};
    float Macc[8] = {1.f, 1.f, 1.f, 1.f, 1.f, 1.f, 1.f, 1.f};
#pragma unroll
    for (int s = 0; s < CS; s++) {
        half8 z = *(const half8*)(Gz + base);
        half8 f = *(const half8*)(Gf + base);
#pragma unroll
        for (int k = 0; k < 8; k++) {
            float fk = (float)f[k], zk = (float)z[k];
            Aacc[k] = fk * zk + (1.f - fk) * Aacc[k];
            Macc[k] = (1.f - fk) * Macc[k];
        }
        base += 16384;
    }
    size_t idx = (size_t)ci * 16384 + (size_t)cg * 8;
    *(f32x4*)(cA + idx)     = *(f32x4*)(Aacc);
    *(f32x4*)(cA + idx + 4) = *(f32x4*)(Aacc + 4);
    *(f32x4*)(cM + idx)     = *(f32x4*)(Macc);
    *(f32x4*)(cM + idx + 4) = *(f32x4*)(Macc + 4);
}

// scan pass 2: scan across NC chunks
__global__ void scan_pass2(const float* __restrict__ cA, const float* __restrict__ cM,
                           float* __restrict__ cIn) {
    int ch = blockIdx.x * 256 + threadIdx.x;   // 16384
    float c = 0.f;
#pragma unroll
    for (int ci = 0; ci < NC; ci++) {
        cIn[ci * 16384 + ch] = c;
        c = cA[ci * 16384 + ch] + cM[ci * 16384 + ch] * c;
    }
}

// scan pass 3: rescan + output gate, x8 vectorized
__global__ void scan_pass3(const _Float16* __restrict__ Gz, const _Float16* __restrict__ Gf,
                           const _Float16* __restrict__ Go, const float* __restrict__ cIn,
                           __bf16* __restrict__ hdst, float* __restrict__ fdst,
                           int is_last) {
    int tid = blockIdx.x * 256 + threadIdx.x;   // 131072
    int ci = tid >> 11;
    int cg = tid & 2047;
    size_t base = (size_t)(ci * CS) * 16384 + (size_t)cg * 8;
    size_t cidx = (size_t)ci * 16384 + (size_t)cg * 8;
    float c[8];
    *(f32x4*)(c)     = *(const f32x4*)(cIn + cidx);
    *(f32x4*)(c + 4) = *(const f32x4*)(cIn + cidx + 4);
#pragma unroll
    for (int s = 0; s < CS; s++) {
        int t = ci * CS + s;
        half8 z = *(const half8*)(Gz + base);
        half8 f = *(const half8*)(Gf + base);
        half8 o = *(const half8*)(Go + base);
        float val[8];
#pragma unroll
        for (int k = 0; k < 8; k++) {
            float fk = (float)f[k];
            c[k] = fk * (float)z[k] + (1.f - fk) * c[k];
            val[k] = (float)o[k] * c[k];
        }
        if (is_last) {
            if (t < T_DIM - 1) {
                *(f32x4*)(fdst + base)     = *(f32x4*)(val);
                *(f32x4*)(fdst + base + 4) = *(f32x4*)(val + 4);
            }
        } else {
            bf16x8 hv;
#pragma unroll
            for (int k = 0; k < 8; k++) hv[k] = f2bf(val[k]);
            *(bf16x8*)(hdst + base) = hv;
        }
        base += 16384;
    }
}

extern "C" void kernel_launch(void* const* d_in, const int* in_sizes, int n_in,
                              void* d_out, int out_size, void* d_ws, size_t ws_size,
                              hipStream_t stream) {
    const int* x = (const int*)d_in[0];
    const float* emb = (const float*)d_in[1];
    const float* W = (const float*)d_in[2];
    const float* b = (const float*)d_in[3];
    float* out = (float*)d_out;

    char* ws = (char*)d_ws;
    size_t need = (size_t)L_DIM * N_DIM * K_DIM * 2
                + (size_t)M_DIM * H_DIM * 2
                + 3ull * M_DIM * H_DIM * 2
                + 3ull * NC * 16384 * 4;
    if (ws_size < need) return;

    __bf16* Wt = (__bf16*)ws;     ws += (size_t)L_DIM * N_DIM * K_DIM * 2;
    __bf16* hbuf = (__bf16*)ws;   ws += (size_t)M_DIM * H_DIM * 2;
    _Float16* Gz = (_Float16*)ws; ws += (size_t)M_DIM * H_DIM * 2;
    _Float16* Gf = (_Float16*)ws; ws += (size_t)M_DIM * H_DIM * 2;
    _Float16* Go = (_Float16*)ws; ws += (size_t)M_DIM * H_DIM * 2;
    float* cA = (float*)ws;       ws += (size_t)NC * 16384 * 4;
    float* cM = (float*)ws;       ws += (size_t)NC * 16384 * 4;
    float* cIn = (float*)ws;

    transpose_w<<<dim3(K_DIM / 32, N_DIM / 32, L_DIM), 256, 0, stream>>>(W, Wt);
    embed_kernel<<<(M_DIM * H_DIM / 4) / 256, 256, 0, stream>>>(x, (const float4*)emb, hbuf);

    for (int l = 0; l < L_DIM; l++) {
        gemm_gates<<<dim3(M_DIM / 128, N_DIM / 128), 256, 0, stream>>>(
            hbuf, Wt + (size_t)l * N_DIM * K_DIM, b + (size_t)l * N_DIM, Gz, Gf, Go);
        scan_pass1<<<(NC * 2048) / 256, 256, 0, stream>>>(Gz, Gf, cA, cM);
        scan_pass2<<<16384 / 256, 256, 0, stream>>>(cA, cM, cIn);
        int last = (l == L_DIM - 1);
        scan_pass3<<<(NC * 2048) / 256, 256, 0, stream>>>(Gz, Gf, Go, cIn, hbuf, out, last);
    }
}

// Round 5
// 559.474 us; speedup vs baseline: 1.1633x; 1.1633x over previous
//
#include <hip/hip_runtime.h>
#include <hip/hip_bf16.h>

#define T_DIM 1024
#define B_DIM 16
#define H_DIM 1024
#define L_DIM 3
#define M_DIM (T_DIM * B_DIM)
#define N_DIM (3 * H_DIM)
#define K_DIM H_DIM
#define NC 64
#define CS 16

typedef __bf16 bf16x8 __attribute__((ext_vector_type(8)));
typedef __bf16 bf16x4 __attribute__((ext_vector_type(4)));
typedef _Float16 half4 __attribute__((ext_vector_type(4)));
typedef float f32x4 __attribute__((ext_vector_type(4)));

__device__ __forceinline__ __bf16 f2bf(float f) {
    return (__bf16)__float2bfloat16(f);
}

__device__ __forceinline__ void async_cp16(const void* g, void* lds) {
    __builtin_amdgcn_global_load_lds(
        (__attribute__((address_space(1))) void*)g,
        (__attribute__((address_space(3))) void*)lds, 16, 0, 0);
}

// ---------- fused prep: W transpose+cast (blocks 0..9215) + embed gather (rest) ----------
#define TW_BLOCKS (32 * 96 * 3)
__global__ void prep_kernel(const float* __restrict__ W, __bf16* __restrict__ Wt,
                            const int* __restrict__ x, const float4* __restrict__ emb,
                            __bf16* __restrict__ h) {
    if (blockIdx.x < TW_BLOCKS) {
        __shared__ __bf16 tile[32][33];
        const int blk = blockIdx.x;
        const int l = blk / 3072;
        const int r2 = blk % 3072;
        const int n0 = (r2 / 32) * 32, k0 = (r2 % 32) * 32;
        const int tx = threadIdx.x & 31, ty = threadIdx.x >> 5;
        const float* Wl = W + (size_t)l * K_DIM * N_DIM;
        __bf16* Wtl = Wt + (size_t)l * N_DIM * K_DIM;
#pragma unroll
        for (int q = 0; q < 4; q++) {
            int k = ty + q * 8;
            tile[k][tx] = f2bf(Wl[(size_t)(k0 + k) * N_DIM + n0 + tx]);
        }
        __syncthreads();
#pragma unroll
        for (int q = 0; q < 4; q++) {
            int n = ty + q * 8;
            Wtl[(size_t)(n0 + n) * K_DIM + k0 + tx] = tile[tx][n];
        }
    } else {
        int i = (blockIdx.x - TW_BLOCKS) * 256 + threadIdx.x;
        int row = i >> 8;
        int j = i & 255;
        int idx = x[row];
        float4 v = emb[(size_t)idx * 256 + j];
        __bf16* dst = h + (size_t)row * H_DIM + j * 4;
        dst[0] = f2bf(v.x); dst[1] = f2bf(v.y); dst[2] = f2bf(v.z); dst[3] = f2bf(v.w);
    }
}

// ---------- GEMM + bias + activation -> fp16 planar gates ----------
// BK=64: 16 K-iterations (half the barriers of BK=32). LDS row = 64 elems = 128 B;
// XOR swizzle slot = chunk ^ (row&7) -> 2 lanes/bank-group per quarter (free).
__global__ __launch_bounds__(256, 2) void gemm_gates(
    const __bf16* __restrict__ A,
    const __bf16* __restrict__ Wt,
    const float* __restrict__ bias,
    _Float16* __restrict__ Gz, _Float16* __restrict__ Gf, _Float16* __restrict__ Go) {
    __shared__ __align__(16) __bf16 As[128 * 64];
    __shared__ __align__(16) __bf16 Bs[128 * 64];

    const int tid = threadIdx.x;
    const int wid = tid >> 6, lane = tid & 63;
    const int bm = blockIdx.x, bn = blockIdx.y;
    const int waveM = wid >> 1, waveN = wid & 1;
    const int lm = lane & 15, kg = lane >> 4;

    // staging: 1024 cells of 16B per matrix, 4 issues of 256 cells.
    // cell = q*256+tid -> row r = cell>>3, lds slot s = cell&7, global chunk g = s^(r&7)
    int roff[4], loff[4];
#pragma unroll
    for (int q = 0; q < 4; q++) {
        int cell = q * 256 + tid;
        int r = cell >> 3, s = cell & 7;
        int g = s ^ (r & 7);
        roff[q] = r * K_DIM + g * 8;           // global elem offset (within k0 slice)
        loff[q] = (q * 256 + wid * 64) * 8;    // wave-uniform LDS elem offset
    }

    const __bf16* Abase = A + (size_t)(bm * 128) * K_DIM;
    const __bf16* Bbase = Wt + (size_t)(bn * 128) * K_DIM;

    f32x4 acc[4][4] = {};

    for (int k0 = 0; k0 < K_DIM; k0 += 64) {
#pragma unroll
        for (int q = 0; q < 4; q++)
            async_cp16(Abase + k0 + roff[q], As + loff[q]);
#pragma unroll
        for (int q = 0; q < 4; q++)
            async_cp16(Bbase + k0 + roff[q], Bs + loff[q]);
        __syncthreads();

#pragma unroll
        for (int h = 0; h < 2; h++) {
            const int cs = ((h * 4 + kg) ^ (lane & 7)) * 8;   // swizzled read chunk
            bf16x8 af[4], bf[4];
#pragma unroll
            for (int i = 0; i < 4; i++)
                af[i] = *(const bf16x8*)(As + (waveM * 64 + i * 16 + lm) * 64 + cs);
#pragma unroll
            for (int j = 0; j < 4; j++)
                bf[j] = *(const bf16x8*)(Bs + (waveN * 64 + j * 16 + lm) * 64 + cs);
#pragma unroll
            for (int i = 0; i < 4; i++)
#pragma unroll
                for (int j = 0; j < 4; j++)
                    acc[i][j] = __builtin_amdgcn_mfma_f32_16x16x32_bf16(af[i], bf[j], acc[i][j], 0, 0, 0);
        }
        __syncthreads();
    }

    // epilogue; plane is block-uniform (bn covers 128 cols inside one 1024-col plane)
    const int plane = bn >> 3;
    _Float16* __restrict__ P = (plane == 0) ? Gz : (plane == 1) ? Gf : Go;
#pragma unroll
    for (int i = 0; i < 4; i++) {
#pragma unroll
        for (int j = 0; j < 4; j++) {
            int ncol = bn * 128 + waveN * 64 + j * 16 + lm;
            int col = ncol & 1023;
            float bv = bias[ncol];
#pragma unroll
            for (int r = 0; r < 4; r++) {
                int mrow = bm * 128 + waveM * 64 + i * 16 + kg * 4 + r;
                float g = acc[i][j][r] + bv;
                float val;
                if (plane == 0) {
                    // tanh(g) = sign(g) * (1 - 2e/(1+e)), e = exp(-2|g|) <= 1
                    float e = __expf(-2.0f * fabsf(g));
                    float rc = __builtin_amdgcn_rcpf(1.0f + e);
                    val = copysignf(fmaf(-2.0f * e, rc, 1.0f), g);
                } else {
                    float e = __expf(-g);
                    val = __builtin_amdgcn_rcpf(1.0f + e);
                }
                P[(size_t)mrow * H_DIM + col] = (_Float16)val;
            }
        }
    }
}

// ---------- scan pass 1: per-chunk affine aggregates, x4 vectorized ----------
__global__ __launch_bounds__(256, 8) void scan_pass1(
    const _Float16* __restrict__ Gz, const _Float16* __restrict__ Gf,
    float* __restrict__ cA, float* __restrict__ cM) {
    int tid = blockIdx.x * 256 + threadIdx.x;   // NC * 4096 = 262144
    int ci = tid >> 12;
    int cg = tid & 4095;                        // channel-group of 4
    size_t base = (size_t)(ci * CS) * 16384 + (size_t)cg * 4;
    f32x4 Aacc = {0.f, 0.f, 0.f, 0.f};
    f32x4 Macc = {1.f, 1.f, 1.f, 1.f};
#pragma unroll
    for (int s = 0; s < CS; s++) {
        half4 z = *(const half4*)(Gz + base);
        half4 f = *(const half4*)(Gf + base);
#pragma unroll
        for (int k = 0; k < 4; k++) {
            float fk = (float)f[k], zk = (float)z[k];
            Aacc[k] = fk * zk + (1.f - fk) * Aacc[k];
            Macc[k] = (1.f - fk) * Macc[k];
        }
        base += 16384;
    }
    size_t idx = (size_t)ci * 16384 + (size_t)cg * 4;
    *(f32x4*)(cA + idx) = Aacc;
    *(f32x4*)(cM + idx) = Macc;
}

// ---------- scan pass 2: scan across NC chunks ----------
__global__ __launch_bounds__(256, 8) void scan_pass2(
    const float* __restrict__ cA, const float* __restrict__ cM,
    float* __restrict__ cIn) {
    int ch = blockIdx.x * 256 + threadIdx.x;   // 16384
    float c = 0.f;
#pragma unroll
    for (int ci = 0; ci < NC; ci++) {
        cIn[ci * 16384 + ch] = c;
        c = cA[ci * 16384 + ch] + cM[ci * 16384 + ch] * c;
    }
}

// ---------- scan pass 3: rescan + output gate, x4 vectorized ----------
__global__ __launch_bounds__(256, 8) void scan_pass3(
    const _Float16* __restrict__ Gz, const _Float16* __restrict__ Gf,
    const _Float16* __restrict__ Go, const float* __restrict__ cIn,
    __bf16* __restrict__ hdst, float* __restrict__ fdst, int is_last) {
    int tid = blockIdx.x * 256 + threadIdx.x;   // 262144
    int ci = tid >> 12;
    int cg = tid & 4095;
    size_t base = (size_t)(ci * CS) * 16384 + (size_t)cg * 4;
    f32x4 c = *(const f32x4*)(cIn + (size_t)ci * 16384 + (size_t)cg * 4);
#pragma unroll
    for (int s = 0; s < CS; s++) {
        int t = ci * CS + s;
        half4 z = *(const half4*)(Gz + base);
        half4 f = *(const half4*)(Gf + base);
        half4 o = *(const half4*)(Go + base);
        f32x4 val;
#pragma unroll
        for (int k = 0; k < 4; k++) {
            float fk = (float)f[k];
            c[k] = fk * (float)z[k] + (1.f - fk) * c[k];
            val[k] = (float)o[k] * c[k];
        }
        if (is_last) {
            if (t < T_DIM - 1)
                *(f32x4*)(fdst + base) = val;
        } else {
            bf16x4 hv;
#pragma unroll
            for (int k = 0; k < 4; k++) hv[k] = f2bf(val[k]);
            *(bf16x4*)(hdst + base) = hv;
        }
        base += 16384;
    }
}

extern "C" void kernel_launch(void* const* d_in, const int* in_sizes, int n_in,
                              void* d_out, int out_size, void* d_ws, size_t ws_size,
                              hipStream_t stream) {
    const int* x = (const int*)d_in[0];
    const float* emb = (const float*)d_in[1];
    const float* W = (const float*)d_in[2];
    const float* b = (const float*)d_in[3];
    float* out = (float*)d_out;

    char* ws = (char*)d_ws;
    size_t need = (size_t)L_DIM * N_DIM * K_DIM * 2
                + (size_t)M_DIM * H_DIM * 2
                + 3ull * M_DIM * H_DIM * 2
                + 3ull * NC * 16384 * 4;
    if (ws_size < need) return;

    __bf16* Wt = (__bf16*)ws;     ws += (size_t)L_DIM * N_DIM * K_DIM * 2;
    __bf16* hbuf = (__bf16*)ws;   ws += (size_t)M_DIM * H_DIM * 2;
    _Float16* Gz = (_Float16*)ws; ws += (size_t)M_DIM * H_DIM * 2;
    _Float16* Gf = (_Float16*)ws; ws += (size_t)M_DIM * H_DIM * 2;
    _Float16* Go = (_Float16*)ws; ws += (size_t)M_DIM * H_DIM * 2;
    float* cA = (float*)ws;       ws += (size_t)NC * 16384 * 4;
    float* cM = (float*)ws;       ws += (size_t)NC * 16384 * 4;
    float* cIn = (float*)ws;

    prep_kernel<<<TW_BLOCKS + 16384, 256, 0, stream>>>(W, Wt, x, (const float4*)emb, hbuf);

    for (int l = 0; l < L_DIM; l++) {
        gemm_gates<<<dim3(M_DIM / 128, N_DIM / 128), 256, 0, stream>>>(
            hbuf, Wt + (size_t)l * N_DIM * K_DIM, b + (size_t)l * N_DIM, Gz, Gf, Go);
        scan_pass1<<<(NC * 4096) / 256, 256, 0, stream>>>(Gz, Gf, cA, cM);
        scan_pass2<<<16384 / 256, 256, 0, stream>>>(cA, cM, cIn);
        int last = (l == L_DIM - 1);
        scan_pass3<<<(NC * 4096) / 256, 256, 0, stream>>>(Gz, Gf, Go, cIn, hbuf, out, last);
    }
}

// Round 7
// 540.531 us; speedup vs baseline: 1.2041x; 1.0350x over previous
//
#include <hip/hip_runtime.h>
#include <hip/hip_bf16.h>
#include <hip/hip_cooperative_groups.h>

namespace coop = cooperative_groups;

#define T_DIM 1024
#define B_DIM 16
#define H_DIM 1024
#define L_DIM 3
#define M_DIM (T_DIM * B_DIM)
#define N_DIM (3 * H_DIM)
#define K_DIM H_DIM
#define NC 64
#define CS 16

typedef __bf16 bf16x8 __attribute__((ext_vector_type(8)));
typedef __bf16 bf16x4 __attribute__((ext_vector_type(4)));
typedef _Float16 half4 __attribute__((ext_vector_type(4)));
typedef float f32x4 __attribute__((ext_vector_type(4)));

__device__ __forceinline__ __bf16 f2bf(float f) {
    return (__bf16)__float2bfloat16(f);
}

__device__ __forceinline__ void async_cp16(const void* g, void* lds) {
    __builtin_amdgcn_global_load_lds(
        (__attribute__((address_space(1))) void*)g,
        (__attribute__((address_space(3))) void*)lds, 16, 0, 0);
}

// ---------- fused prep: W transpose+cast (blocks 0..9215) + embed gather (rest) ----------
#define TW_BLOCKS (32 * 96 * 3)
__global__ void prep_kernel(const float* __restrict__ W, __bf16* __restrict__ Wt,
                            const int* __restrict__ x, const float4* __restrict__ emb,
                            __bf16* __restrict__ h) {
    if (blockIdx.x < TW_BLOCKS) {
        __shared__ __bf16 tile[32][33];
        const int blk = blockIdx.x;
        const int l = blk / 3072;
        const int r2 = blk % 3072;
        const int n0 = (r2 / 32) * 32, k0 = (r2 % 32) * 32;
        const int tx = threadIdx.x & 31, ty = threadIdx.x >> 5;
        const float* Wl = W + (size_t)l * K_DIM * N_DIM;
        __bf16* Wtl = Wt + (size_t)l * N_DIM * K_DIM;
#pragma unroll
        for (int q = 0; q < 4; q++) {
            int k = ty + q * 8;
            tile[k][tx] = f2bf(Wl[(size_t)(k0 + k) * N_DIM + n0 + tx]);
        }
        __syncthreads();
#pragma unroll
        for (int q = 0; q < 4; q++) {
            int n = ty + q * 8;
            Wtl[(size_t)(n0 + n) * K_DIM + k0 + tx] = tile[tx][n];
        }
    } else {
        int i = (blockIdx.x - TW_BLOCKS) * 256 + threadIdx.x;
        int row = i >> 8;
        int j = i & 255;
        int idx = x[row];
        float4 v = emb[(size_t)idx * 256 + j];
        __bf16* dst = h + (size_t)row * H_DIM + j * 4;
        dst[0] = f2bf(v.x); dst[1] = f2bf(v.y); dst[2] = f2bf(v.z); dst[3] = f2bf(v.w);
    }
}

// ---------- GEMM + bias + activation -> fp16 planar gates ----------
// BK=64: 16 K-iterations. LDS row = 64 elems = 128 B;
// XOR swizzle slot = chunk ^ (row&7) -> 2 lanes/bank-group per quarter (free).
__global__ __launch_bounds__(256, 2) void gemm_gates(
    const __bf16* __restrict__ A,
    const __bf16* __restrict__ Wt,
    const float* __restrict__ bias,
    _Float16* __restrict__ Gz, _Float16* __restrict__ Gf, _Float16* __restrict__ Go) {
    __shared__ __align__(16) __bf16 As[128 * 64];
    __shared__ __align__(16) __bf16 Bs[128 * 64];

    const int tid = threadIdx.x;
    const int wid = tid >> 6, lane = tid & 63;
    const int bm = blockIdx.x, bn = blockIdx.y;
    const int waveM = wid >> 1, waveN = wid & 1;
    const int lm = lane & 15, kg = lane >> 4;

    int roff[4], loff[4];
#pragma unroll
    for (int q = 0; q < 4; q++) {
        int cell = q * 256 + tid;
        int r = cell >> 3, s = cell & 7;
        int g = s ^ (r & 7);
        roff[q] = r * K_DIM + g * 8;           // global elem offset (within k0 slice)
        loff[q] = (q * 256 + wid * 64) * 8;    // wave-uniform LDS elem offset
    }

    const __bf16* Abase = A + (size_t)(bm * 128) * K_DIM;
    const __bf16* Bbase = Wt + (size_t)(bn * 128) * K_DIM;

    f32x4 acc[4][4] = {};

    for (int k0 = 0; k0 < K_DIM; k0 += 64) {
#pragma unroll
        for (int q = 0; q < 4; q++)
            async_cp16(Abase + k0 + roff[q], As + loff[q]);
#pragma unroll
        for (int q = 0; q < 4; q++)
            async_cp16(Bbase + k0 + roff[q], Bs + loff[q]);
        __syncthreads();

#pragma unroll
        for (int h = 0; h < 2; h++) {
            const int cs = ((h * 4 + kg) ^ (lane & 7)) * 8;   // swizzled read chunk
            bf16x8 af[4], bf[4];
#pragma unroll
            for (int i = 0; i < 4; i++)
                af[i] = *(const bf16x8*)(As + (waveM * 64 + i * 16 + lm) * 64 + cs);
#pragma unroll
            for (int j = 0; j < 4; j++)
                bf[j] = *(const bf16x8*)(Bs + (waveN * 64 + j * 16 + lm) * 64 + cs);
#pragma unroll
            for (int i = 0; i < 4; i++)
#pragma unroll
                for (int j = 0; j < 4; j++)
                    acc[i][j] = __builtin_amdgcn_mfma_f32_16x16x32_bf16(af[i], bf[j], acc[i][j], 0, 0, 0);
        }
        __syncthreads();
    }

    // epilogue; plane is block-uniform (bn covers 128 cols inside one 1024-col plane)
    const int plane = bn >> 3;
    _Float16* __restrict__ P = (plane == 0) ? Gz : (plane == 1) ? Gf : Go;
#pragma unroll
    for (int i = 0; i < 4; i++) {
#pragma unroll
        for (int j = 0; j < 4; j++) {
            int ncol = bn * 128 + waveN * 64 + j * 16 + lm;
            int col = ncol & 1023;
            float bv = bias[ncol];
#pragma unroll
            for (int r = 0; r < 4; r++) {
                int mrow = bm * 128 + waveM * 64 + i * 16 + kg * 4 + r;
                float g = acc[i][j][r] + bv;
                float val;
                if (plane == 0) {
                    // tanh(g) = sign(g) * (1 - 2e/(1+e)), e = exp(-2|g|) <= 1
                    float e = __expf(-2.0f * fabsf(g));
                    float rc = __builtin_amdgcn_rcpf(1.0f + e);
                    val = copysignf(fmaf(-2.0f * e, rc, 1.0f), g);
                } else {
                    float e = __expf(-g);
                    val = __builtin_amdgcn_rcpf(1.0f + e);
                }
                P[(size_t)mrow * H_DIM + col] = (_Float16)val;
            }
        }
    }
}

// ---------- coop fused scan: pass1 (regs kept) + grid.sync + redundant fold + pass3 ----------
// grid MUST be 1024 blocks x 256 threads, all co-resident (guarded by occupancy query).
__global__ __launch_bounds__(256, 4) void scan_fused(
    const _Float16* __restrict__ Gz, const _Float16* __restrict__ Gf,
    const _Float16* __restrict__ Go,
    float* __restrict__ cA, float* __restrict__ cM,
    __bf16* __restrict__ hdst, float* __restrict__ fdst, int is_last) {
    int tidg = blockIdx.x * 256 + threadIdx.x;   // 262144
    int ci = tidg >> 12;                         // chunk 0..63
    int chg = tidg & 4095;                       // channel-group of 4
    size_t base = (size_t)(ci * CS) * 16384 + (size_t)chg * 4;

    // phase 1: local chunk aggregates; keep z,f in registers (16 x 2 x half4 = 64 VGPRs)
    half4 zs[CS], fs[CS];
    f32x4 Aacc = {0.f, 0.f, 0.f, 0.f};
    f32x4 Macc = {1.f, 1.f, 1.f, 1.f};
    {
        size_t p = base;
#pragma unroll
        for (int s = 0; s < CS; s++) {
            zs[s] = *(const half4*)(Gz + p);
            fs[s] = *(const half4*)(Gf + p);
#pragma unroll
            for (int k = 0; k < 4; k++) {
                float fk = (float)fs[s][k], zk = (float)zs[s][k];
                Aacc[k] = fk * zk + (1.f - fk) * Aacc[k];
                Macc[k] = (1.f - fk) * Macc[k];
            }
            p += 16384;
        }
    }
    size_t idx = (size_t)ci * 16384 + (size_t)chg * 4;
    *(f32x4*)(cA + idx) = Aacc;
    *(f32x4*)(cM + idx) = Macc;

    __threadfence();                 // device-scope release of cA/cM
    coop::this_grid().sync();

    // phase 2: fold prior chunks' aggregates (cA/cM L2-hot, 8 MB)
    f32x4 c = {0.f, 0.f, 0.f, 0.f};
    for (int cj = 0; cj < ci; cj++) {
        size_t jdx = (size_t)cj * 16384 + (size_t)chg * 4;
        f32x4 a = *(const f32x4*)(cA + jdx);
        f32x4 m = *(const f32x4*)(cM + jdx);
#pragma unroll
        for (int k = 0; k < 4; k++) c[k] = a[k] + m[k] * c[k];
    }

    // phase 3: rescan from registers + output gate (only o is loaded)
    size_t p = base;
#pragma unroll
    for (int s = 0; s < CS; s++) {
        int t = ci * CS + s;
        half4 o = *(const half4*)(Go + p);
        f32x4 val;
#pragma unroll
        for (int k = 0; k < 4; k++) {
            float fk = (float)fs[s][k];
            c[k] = fk * (float)zs[s][k] + (1.f - fk) * c[k];
            val[k] = (float)o[k] * c[k];
        }
        if (is_last) {
            if (t < T_DIM - 1)
                *(f32x4*)(fdst + p) = val;
        } else {
            bf16x4 hv;
#pragma unroll
            for (int k = 0; k < 4; k++) hv[k] = f2bf(val[k]);
            *(bf16x4*)(hdst + p) = hv;
        }
        p += 16384;
    }
}

// ---------- fallback pass 1: per-chunk affine aggregates ----------
__global__ __launch_bounds__(256, 8) void scan_pass1(
    const _Float16* __restrict__ Gz, const _Float16* __restrict__ Gf,
    float* __restrict__ cA, float* __restrict__ cM) {
    int tidg = blockIdx.x * 256 + threadIdx.x;   // 262144
    int ci = tidg >> 12;
    int chg = tidg & 4095;
    size_t base = (size_t)(ci * CS) * 16384 + (size_t)chg * 4;
    f32x4 Aacc = {0.f, 0.f, 0.f, 0.f};
    f32x4 Macc = {1.f, 1.f, 1.f, 1.f};
#pragma unroll
    for (int s = 0; s < CS; s++) {
        half4 z = *(const half4*)(Gz + base);
        half4 f = *(const half4*)(Gf + base);
#pragma unroll
        for (int k = 0; k < 4; k++) {
            float fk = (float)f[k], zk = (float)z[k];
            Aacc[k] = fk * zk + (1.f - fk) * Aacc[k];
            Macc[k] = (1.f - fk) * Macc[k];
        }
        base += 16384;
    }
    size_t idx = (size_t)ci * 16384 + (size_t)chg * 4;
    *(f32x4*)(cA + idx) = Aacc;
    *(f32x4*)(cM + idx) = Macc;
}

// ---------- fallback pass 2+3: redundant chunk-prefix fold + rescan + o-gate ----------
__global__ __launch_bounds__(256, 8) void scan_pass23(
    const _Float16* __restrict__ Gz, const _Float16* __restrict__ Gf,
    const _Float16* __restrict__ Go,
    const float* __restrict__ cA, const float* __restrict__ cM,
    __bf16* __restrict__ hdst, float* __restrict__ fdst, int is_last) {
    int tidg = blockIdx.x * 256 + threadIdx.x;   // 262144
    int ci = tidg >> 12;                         // uniform per block
    int chg = tidg & 4095;
    // fold prior chunks' aggregates (same order as coop path -> bit-identical)
    f32x4 c = {0.f, 0.f, 0.f, 0.f};
    for (int cj = 0; cj < ci; cj++) {
        size_t jdx = (size_t)cj * 16384 + (size_t)chg * 4;
        f32x4 a = *(const f32x4*)(cA + jdx);
        f32x4 m = *(const f32x4*)(cM + jdx);
#pragma unroll
        for (int k = 0; k < 4; k++) c[k] = a[k] + m[k] * c[k];
    }
    size_t p = (size_t)(ci * CS) * 16384 + (size_t)chg * 4;
#pragma unroll
    for (int s = 0; s < CS; s++) {
        int t = ci * CS + s;
        half4 z = *(const half4*)(Gz + p);
        half4 f = *(const half4*)(Gf + p);
        half4 o = *(const half4*)(Go + p);
        f32x4 val;
#pragma unroll
        for (int k = 0; k < 4; k++) {
            float fk = (float)f[k];
            c[k] = fk * (float)z[k] + (1.f - fk) * c[k];
            val[k] = (float)o[k] * c[k];
        }
        if (is_last) {
            if (t < T_DIM - 1)
                *(f32x4*)(fdst + p) = val;
        } else {
            bf16x4 hv;
#pragma unroll
            for (int k = 0; k < 4; k++) hv[k] = f2bf(val[k]);
            *(bf16x4*)(hdst + p) = hv;
        }
        p += 16384;
    }
}

extern "C" void kernel_launch(void* const* d_in, const int* in_sizes, int n_in,
                              void* d_out, int out_size, void* d_ws, size_t ws_size,
                              hipStream_t stream) {
    const int* x = (const int*)d_in[0];
    const float* emb = (const float*)d_in[1];
    const float* W = (const float*)d_in[2];
    const float* b = (const float*)d_in[3];
    float* out = (float*)d_out;

    char* ws = (char*)d_ws;
    size_t need = (size_t)L_DIM * N_DIM * K_DIM * 2
                + (size_t)M_DIM * H_DIM * 2
                + 3ull * M_DIM * H_DIM * 2
                + 2ull * NC * 16384 * 4;
    if (ws_size < need) return;

    __bf16* Wt = (__bf16*)ws;     ws += (size_t)L_DIM * N_DIM * K_DIM * 2;
    __bf16* hbuf = (__bf16*)ws;   ws += (size_t)M_DIM * H_DIM * 2;
    _Float16* Gz = (_Float16*)ws; ws += (size_t)M_DIM * H_DIM * 2;
    _Float16* Gf = (_Float16*)ws; ws += (size_t)M_DIM * H_DIM * 2;
    _Float16* Go = (_Float16*)ws; ws += (size_t)M_DIM * H_DIM * 2;
    float* cA = (float*)ws;       ws += (size_t)NC * 16384 * 4;
    float* cM = (float*)ws;

    // host-side, capture-safe, deterministic: can 1024 coop blocks be co-resident?
    int blocksPerCU = 0;
    hipError_t qe = hipOccupancyMaxActiveBlocksPerMultiprocessor(
        &blocksPerCU, (const void*)scan_fused, 256, 0);
    const bool use_coop = (qe == hipSuccess && blocksPerCU >= 4);

    prep_kernel<<<TW_BLOCKS + 16384, 256, 0, stream>>>(W, Wt, x, (const float4*)emb, hbuf);

    for (int l = 0; l < L_DIM; l++) {
        gemm_gates<<<dim3(M_DIM / 128, N_DIM / 128), 256, 0, stream>>>(
            hbuf, Wt + (size_t)l * N_DIM * K_DIM, b + (size_t)l * N_DIM, Gz, Gf, Go);
        int last = (l == L_DIM - 1);

        bool launched = false;
        if (use_coop) {
            const _Float16* aGz = Gz; const _Float16* aGf = Gf; const _Float16* aGo = Go;
            float* acA = cA; float* acM = cM;
            __bf16* ah = hbuf; float* af = out;
            void* args[] = {(void*)&aGz, (void*)&aGf, (void*)&aGo,
                            (void*)&acA, (void*)&acM, (void*)&ah, (void*)&af, (void*)&last};
            hipError_t e = hipLaunchCooperativeKernel((const void*)scan_fused,
                                                      dim3(1024), dim3(256), args, 0, stream);
            launched = (e == hipSuccess);
        }
        if (!launched) {
            scan_pass1<<<1024, 256, 0, stream>>>(Gz, Gf, cA, cM);
            scan_pass23<<<1024, 256, 0, stream>>>(Gz, Gf, Go, cA, cM, hbuf, out, last);
        }
    }
}